// Round 1
// 1061.229 us; speedup vs baseline: 1.1963x; 1.1963x over previous
//
#include <hip/hip_runtime.h>
#include <hip/hip_bf16.h>
#include <string.h>

#define NPT   16384
#define NBAT  16
#define CH    288
#define SP    256
#define KS    16
#define OFF_FEAT 12288L
#define OFF_IND  1191936L

// ---------- helpers ----------
__device__ __forceinline__ float bfbits(unsigned short u){
  unsigned int x = ((unsigned int)u) << 16; float f; __builtin_memcpy(&f,&x,4); return f;
}
__device__ __forceinline__ float ldf(const void* p, long i, int isb){
  if (isb) return __bfloat162float(((const __hip_bfloat16*)p)[i]);
  return ((const float*)p)[i];
}
__device__ __forceinline__ void sto(void* p, long i, float v, int isb){
  if (isb) ((__hip_bfloat16*)p)[i] = __float2bfloat16(v);
  else     ((float*)p)[i] = v;
}
__device__ __forceinline__ void gload_lds(const void* g, void* l){
  __builtin_amdgcn_global_load_lds((const __attribute__((address_space(1))) void*)g,
      (__attribute__((address_space(3))) void*)l, 16, 0, 0);
}

typedef __attribute__((ext_vector_type(8))) short bf16x8;
typedef __attribute__((ext_vector_type(4))) float f32x4;

// ---------- 0. input dtype detection ----------
__global__ void detect_k(const void* __restrict__ xyz, int* __restrict__ flag){
  __shared__ float red[256];
  const int t = threadIdx.x;
  const unsigned short* u = (const unsigned short*)xyz;
  float m = 0.f;
  for (int i = t; i < 4096; i += 256){
    float f = fabsf(bfbits(u[i]));
    if (f != f) f = 1e30f;
    m = fmaxf(m, f);
  }
  red[t] = m; __syncthreads();
  for (int s = 128; s; s >>= 1){ if (t < s) red[t] = fmaxf(red[t], red[t+s]); __syncthreads(); }
  if (t == 0) *flag = (red[0] < 2.0f) ? 1 : 0;
}

// ---------- 0b. xyz -> f32 SoA ----------
__global__ __launch_bounds__(256) void cvtxyz_k(const void* __restrict__ xyz,
    const int* __restrict__ flag, float* __restrict__ X, float* __restrict__ Y,
    float* __restrict__ Z){
  const int e = blockIdx.x*256 + threadIdx.x;       // < 786432
  const int isb = *flag;
  float v = ldf(xyz, e, isb);
  int b = e / (NPT*3), r = e - b*(NPT*3), i = r/3, c = r - i*3;
  float* P = (c==0) ? X : ((c==1) ? Y : Z);
  P[b*NPT + i] = v;
}

// ---------- 0c. W -> bf16 [288][296] + BN scale/shift ----------
__global__ __launch_bounds__(256) void cvtw_k(const void* __restrict__ W,
    const void* __restrict__ g, const void* __restrict__ bb,
    const void* __restrict__ m, const void* __restrict__ v,
    const int* __restrict__ flag, __hip_bfloat16* __restrict__ Wbf,
    float* __restrict__ scale, float* __restrict__ shift, int Kin){
  const int isb = *flag;
  const int idx = blockIdx.x*256 + threadIdx.x;
  if (idx < 288*296){
    int o = idx / 296, k = idx - o*296;
    float val = (k < Kin) ? ldf(W, (long)o*Kin + k, isb) : 0.f;
    Wbf[idx] = __float2bfloat16(val);
  }
  if (idx < 288){
    float sc = ldf(g, idx, isb) * rsqrtf(ldf(v, idx, isb) + 1e-5f);
    scale[idx] = sc;
    shift[idx] = ldf(bb, idx, isb) - ldf(m, idx, isb)*sc;
  }
}

// ---------- 1. FPS: 1024 thr x 16 pts in registers, u64 packed argmax ----------
// key = (f32 bits of dist) << 32 | (16383 - idx): larger key == farther point,
// exact first-index tie-break (dist >= 0 so bit pattern is order-preserving).
// One barrier/iter (double-buffered wave-key slots); outputs buffered in LDS,
// flushed once at the end (no per-iter global stores -> free vmcnt drain).
__global__ __launch_bounds__(1024) __attribute__((amdgpu_waves_per_eu(4,4)))
void fps_k(const float* __restrict__ X,
    const float* __restrict__ Y, const float* __restrict__ Z,
    const int* __restrict__ flag, float* __restrict__ nxyz, void* __restrict__ dout){
  #pragma clang fp contract(off)
  const int b = blockIdx.x, t = threadIdx.x;
  const int base = b*NPT;
  float px[16], py[16], pz[16], dist[16];
  #pragma unroll
  for (int i=0;i<16;i++){
    px[i] = X[base + t + i*1024];
    py[i] = Y[base + t + i*1024];
    pz[i] = Z[base + t + i*1024];
    dist[i] = 1e10f;
  }
  __shared__ unsigned long long rk[2][16];
  __shared__ float ox[SP], oy[SP], oz[SP];
  __shared__ int   oi[SP];
  const int lane = t & 63, wid = t >> 6;
  const unsigned int lbase = 16383u - (unsigned int)t;
  float cx = X[base], cy = Y[base], cz = Z[base];
  int cur = 0;
  for (int it=0; it<SP; it++){
    if (t == 0){ ox[it]=cx; oy[it]=cy; oz[it]=cz; oi[it]=cur; }
    unsigned long long best = 0ull;
    #pragma unroll
    for (int i=0;i<16;i++){
      float dx = px[i]-cx, dy = py[i]-cy, dz = pz[i]-cz;
      float d2 = dx*dx + dy*dy; d2 = d2 + dz*dz;
      float dn = fminf(dist[i], d2); dist[i] = dn;
      unsigned long long key = ((unsigned long long)__float_as_uint(dn) << 32)
                             | (unsigned long long)(lbase - (unsigned int)(i*1024));
      best = (key > best) ? key : best;
    }
    // intra-wave reduce (lane 0's dependency cone never touches OOB lanes)
    #pragma unroll
    for (int off=32; off; off>>=1){
      unsigned long long o = __shfl_down(best, off, 64);
      best = (o > best) ? o : best;
    }
    const int p = it & 1;
    if (lane == 0) rk[p][wid] = best;
    __syncthreads();
    // all-thread redundant 16-way reduce (4 parallel chains -> shallow deps)
    unsigned long long g0 = rk[p][0], g1 = rk[p][1], g2 = rk[p][2], g3 = rk[p][3];
    #pragma unroll
    for (int w=4; w<16; w+=4){
      unsigned long long a0=rk[p][w], a1=rk[p][w+1], a2=rk[p][w+2], a3=rk[p][w+3];
      g0=(a0>g0)?a0:g0; g1=(a1>g1)?a1:g1; g2=(a2>g2)?a2:g2; g3=(a3>g3)?a3:g3;
    }
    g0=(g1>g0)?g1:g0; g2=(g3>g2)?g3:g2; g0=(g2>g0)?g2:g0;
    cur = 16383 - (int)(unsigned int)g0;
    cx = X[base+cur]; cy = Y[base+cur]; cz = Z[base+cur];
  }
  __syncthreads();
  if (t < SP){
    const int isb = *flag;
    const long bs = (long)b*SP + t;
    float fx=ox[t], fy=oy[t], fz=oz[t]; int ii=oi[t];
    nxyz[bs*3+0]=fx; nxyz[bs*3+1]=fy; nxyz[bs*3+2]=fz;
    sto(dout, bs*3+0, fx, isb);
    sto(dout, bs*3+1, fy, isb);
    sto(dout, bs*3+2, fz, isb);
    sto(dout, OFF_IND + bs, (float)ii, isb);
  }
}

// ---------- 2. ball query (SoA f32) ----------
__global__ __launch_bounds__(256) void ballq_k(const float* __restrict__ X,
    const float* __restrict__ Y, const float* __restrict__ Z,
    const float* __restrict__ nxyz, int* __restrict__ bidx){
  #pragma clang fp contract(off)
  const int gw = (blockIdx.x*256 + threadIdx.x) >> 6;
  const int lane = threadIdx.x & 63;
  const int b = gw >> 8, base = b*NPT;
  const float cx = nxyz[gw*3+0], cy = nxyz[gw*3+1], cz = nxyz[gw*3+2];
  int cnt = 0, first = 0; bool havef = false;
  for (int st = 0; st < NPT && cnt < KS; st += 64){
    const int id = st + lane;
    float dx = X[base+id]-cx, dy = Y[base+id]-cy, dz = Z[base+id]-cz;
    float d2 = dx*dx + dy*dy; d2 = d2 + dz*dz;
    unsigned long long mk = __ballot(d2 <= 0.09f);  // == (f32 d2 < double 0.09)
    if (mk){
      if (!havef){ first = st + __builtin_ctzll(mk); havef = true; }
      int rank = cnt + __popcll(mk & ((1ull<<lane)-1ull));
      if (((mk>>lane)&1ull) && rank < KS) bidx[gw*KS + rank] = id;
      cnt += __popcll(mk);
    }
  }
  if (cnt < KS && lane >= cnt && lane < KS) bidx[gw*KS + lane] = first;
}

// ---------- 3. gather -> h0 [n][296] bf16 via LDS tile ----------
__global__ __launch_bounds__(256) void gather_k(const void* __restrict__ xyz,
    const void* __restrict__ feat, const int* __restrict__ flag,
    const int* __restrict__ bidx, const float* __restrict__ nxyz,
    __hip_bfloat16* __restrict__ h0){
  __shared__ __hip_bfloat16 tile[64*296];
  const int isb = *flag;
  const int t = threadIdx.x, n0 = blockIdx.x*64;
  const int nl = t >> 2, cg = t & 3;
  const int n = n0 + nl, b = n >> 12, s = n >> 4;
  const int id = bidx[n];
  for (int j=0; j<74; j++){
    int c = cg*74 + j;
    float vv = 0.f;
    if (c < 3)       vv = (ldf(xyz, ((long)b*NPT + id)*3 + c, isb) - nxyz[(long)s*3 + c]) / 0.3f;
    else if (c < 291) vv = ldf(feat, ((long)b*CH + (c-3))*(long)NPT + id, isb);
    tile[nl*296 + c] = __float2bfloat16(vv);
  }
  __syncthreads();
  const uint4* src = (const uint4*)tile;
  uint4* dst = (uint4*)((char*)h0 + (long)n0*592);
  for (int j = t; j < 2368; j += 256) dst[j] = src[j];
}

// ---------- 4. MFMA GEMM: Out[n][o] = relu(BN(sum_k A[n][k]*W[o][k])) ----------
// Block tile 128n x 96o, whole-K A-tile in LDS (global_load_lds), W frags from L2.
__global__ __launch_bounds__(256, 2) void gemm_k(
    const __hip_bfloat16* __restrict__ A, int astr,
    const __hip_bfloat16* __restrict__ W,
    const float* __restrict__ scale, const float* __restrict__ shift,
    __hip_bfloat16* __restrict__ Out, int ostr,
    int ktiles, int kvalid){
  extern __shared__ char lds[];
  const int t = threadIdx.x, lane = t & 63, wid = t >> 6;
  const int wm = wid & 1, wo = wid >> 1;
  const int bx = blockIdx.x, by = blockIdx.y;
  {
    const char* src = (const char*)(A + (long)bx*128*astr);
    const int chunks = (128*astr*2) >> 10;
    for (int c = wid; c < chunks; c += 4)
      gload_lds(src + c*1024 + lane*16, lds + c*1024);
  }
  f32x4 acc[4][3];
  #pragma unroll
  for (int mf=0; mf<4; mf++)
    #pragma unroll
    for (int of=0; of<3; of++) acc[mf][of] = (f32x4){0.f,0.f,0.f,0.f};

  const int mrow  = wm*64 + (lane & 15);
  const int kg    = (lane >> 4) * 8;
  const int obase = by*96 + wo*48 + (lane & 15);
  __syncthreads();

  for (int kt = 0; kt < ktiles; kt++){
    const int k0 = kt*32 + kg;
    const bool z = (k0 >= kvalid);
    const int k0c = z ? 0 : k0;
    bf16x8 a[4], bf[3];
    #pragma unroll
    for (int mf=0; mf<4; mf++)
      a[mf] = *(const bf16x8*)(lds + ((long)(mrow + mf*16)*astr + k0c)*2);
    if (z){
      bf16x8 zz = {0,0,0,0,0,0,0,0};
      #pragma unroll
      for (int mf=0; mf<4; mf++) a[mf] = zz;
    }
    #pragma unroll
    for (int of=0; of<3; of++)
      bf[of] = *(const bf16x8*)(W + (long)(obase + of*16)*296 + k0c);
    #pragma unroll
    for (int mf=0; mf<4; mf++)
      #pragma unroll
      for (int of=0; of<3; of++)
        acc[mf][of] = __builtin_amdgcn_mfma_f32_16x16x32_bf16(a[mf], bf[of], acc[mf][of], 0, 0, 0);
  }

  float sc[3], sh[3];
  #pragma unroll
  for (int of=0; of<3; of++){ sc[of] = scale[obase + of*16]; sh[of] = shift[obase + of*16]; }
  #pragma unroll
  for (int mf=0; mf<4; mf++)
    #pragma unroll
    for (int of=0; of<3; of++)
      #pragma unroll
      for (int r=0; r<4; r++){
        const long row = (long)bx*128 + wm*64 + mf*16 + (lane>>4)*4 + r;
        const int o = obase + of*16;
        float vv = acc[mf][of][r]*sc[of] + sh[of];
        Out[row*ostr + o] = __float2bfloat16(fmaxf(vv, 0.f));
      }
}

// ---------- 5. maxpool over k: h[n][288] -> out[b][o][s] ----------
__global__ __launch_bounds__(256) void maxk_k(const __hip_bfloat16* __restrict__ h,
    const int* __restrict__ flag, void* __restrict__ dout){
  __shared__ __hip_bfloat16 tile[128*288];
  const int isb = *flag;
  const int t = threadIdx.x;
  const int b = blockIdx.x >> 5, s0 = (blockIdx.x & 31)*8;
  const long n0 = (long)b*4096 + (long)s0*16;
  {
    const char* src = (const char*)(h + n0*288);
    for (int c = (t>>6); c < 72; c += 4)
      gload_lds(src + c*1024 + (t&63)*16, (char*)tile + c*1024);
  }
  __syncthreads();
  for (int o = t; o < 288; o += 256){
    float mx[8];
    #pragma unroll
    for (int sl=0; sl<8; sl++){
      float m = -1e30f;
      #pragma unroll
      for (int kk=0; kk<16; kk++)
        m = fmaxf(m, __bfloat162float(tile[(sl*16 + kk)*288 + o]));
      mx[sl] = m;
    }
    const long e0 = OFF_FEAT + (long)b*73728 + (long)o*256 + s0;
    if (isb){
      unsigned short u[8];
      #pragma unroll
      for (int sl=0; sl<8; sl++){
        __hip_bfloat16 hb = __float2bfloat16(mx[sl]);
        __builtin_memcpy(&u[sl], &hb, 2);
      }
      uint4 pk; __builtin_memcpy(&pk, u, 16);
      *(uint4*)((__hip_bfloat16*)dout + e0) = pk;
    } else {
      float* fo = (float*)dout + e0;
      *(float4*)fo     = make_float4(mx[0],mx[1],mx[2],mx[3]);
      *(float4*)(fo+4) = make_float4(mx[4],mx[5],mx[6],mx[7]);
    }
  }
}

extern "C" void kernel_launch(void* const* d_in, const int* in_sizes, int n_in,
                              void* d_out, int out_size, void* d_ws, size_t ws_size,
                              hipStream_t stream){
  const void* xyz  = d_in[0];
  const void* feat = d_in[1];
  const void* W0 = d_in[2];  const void* g0 = d_in[3];  const void* b0 = d_in[4];
  const void* m0 = d_in[5];  const void* v0 = d_in[6];
  const void* W1 = d_in[7];  const void* g1 = d_in[8];  const void* b1 = d_in[9];
  const void* m1 = d_in[10]; const void* v1 = d_in[11];
  const void* W2 = d_in[12]; const void* g2 = d_in[13]; const void* b2 = d_in[14];
  const void* m2 = d_in[15]; const void* v2 = d_in[16];

  char* ws = (char*)d_ws;
  int*   flag  = (int*)ws;                                   // [0,64)
  float* sc0   = (float*)(ws + 64);                          // 3x(288+288) f32
  float* sh0   = sc0 + 288;
  float* sc1   = sc0 + 576;  float* sh1 = sc0 + 864;
  float* sc2   = sc0 + 1152; float* sh2 = sc0 + 1440;
  __hip_bfloat16* Wb0 = (__hip_bfloat16*)(ws + 7040);        // 288*296*2 = 170496
  __hip_bfloat16* Wb1 = Wb0 + 288*296;
  __hip_bfloat16* Wb2 = Wb1 + 288*296;                       // ends @ 518528
  float* nxyz = (float*)(ws + 518656);                       // 49152 -> 567808
  int*   bidx = (int*)(ws + 567808);                         // 262144 -> 829952
  float* X    = (float*)(ws + 1048576);                      // overlaid with bufA (dead after ballq)
  float* Y    = X + NBAT*NPT;
  float* Z    = Y + NBAT*NPT;
  __hip_bfloat16* bufA = (__hip_bfloat16*)(ws + 1048576);    // [65536][296] = 38797312
  __hip_bfloat16* bufB = (__hip_bfloat16*)(ws + 1048576 + 38797312); // [65536][288] -> end 77594624

  detect_k<<<1, 256, 0, stream>>>(xyz, flag);
  cvtxyz_k<<<3072, 256, 0, stream>>>(xyz, flag, X, Y, Z);
  cvtw_k<<<333, 256, 0, stream>>>(W0, g0, b0, m0, v0, flag, Wb0, sc0, sh0, 291);
  cvtw_k<<<333, 256, 0, stream>>>(W1, g1, b1, m1, v1, flag, Wb1, sc1, sh1, 288);
  cvtw_k<<<333, 256, 0, stream>>>(W2, g2, b2, m2, v2, flag, Wb2, sc2, sh2, 288);
  fps_k<<<NBAT, 1024, 0, stream>>>(X, Y, Z, flag, nxyz, d_out);
  ballq_k<<<1024, 256, 0, stream>>>(X, Y, Z, nxyz, bidx);
  gather_k<<<1024, 256, 0, stream>>>(xyz, feat, flag, bidx, nxyz, bufA);
  gemm_k<<<dim3(512,3), 256, 128*296*2, stream>>>(bufA, 296, Wb0, sc0, sh0, bufB, 288, 10, 296);
  gemm_k<<<dim3(512,3), 256, 128*288*2, stream>>>(bufB, 288, Wb1, sc1, sh1, bufA, 296, 9, 288);
  gemm_k<<<dim3(512,3), 256, 128*296*2, stream>>>(bufA, 296, Wb2, sc2, sh2, bufB, 288, 9, 288);
  maxk_k<<<512, 256, 0, stream>>>(bufB, flag, d_out);
}

// Round 2
// 1012.405 us; speedup vs baseline: 1.2540x; 1.0482x over previous
//
#include <hip/hip_runtime.h>
#include <hip/hip_bf16.h>
#include <string.h>

#define NPT   16384
#define NBAT  16
#define CH    288
#define SP    256
#define KS    16
#define OFF_FEAT 12288L
#define OFF_IND  1191936L

// ---------- helpers ----------
__device__ __forceinline__ float bfbits(unsigned short u){
  unsigned int x = ((unsigned int)u) << 16; float f; __builtin_memcpy(&f,&x,4); return f;
}
__device__ __forceinline__ float ldf(const void* p, long i, int isb){
  if (isb) return __bfloat162float(((const __hip_bfloat16*)p)[i]);
  return ((const float*)p)[i];
}
__device__ __forceinline__ void sto(void* p, long i, float v, int isb){
  if (isb) ((__hip_bfloat16*)p)[i] = __float2bfloat16(v);
  else     ((float*)p)[i] = v;
}
__device__ __forceinline__ void gload_lds(const void* g, void* l){
  __builtin_amdgcn_global_load_lds((const __attribute__((address_space(1))) void*)g,
      (__attribute__((address_space(3))) void*)l, 16, 0, 0);
}
__device__ __forceinline__ unsigned spread4(unsigned x){
  return (x&1u) | ((x&2u)<<2) | ((x&4u)<<4) | ((x&8u)<<6);
}

typedef __attribute__((ext_vector_type(8))) short bf16x8;
typedef __attribute__((ext_vector_type(4))) float f32x4;

// ---------- 0. input dtype detection ----------
__global__ void detect_k(const void* __restrict__ xyz, int* __restrict__ flag){
  __shared__ float red[256];
  const int t = threadIdx.x;
  const unsigned short* u = (const unsigned short*)xyz;
  float m = 0.f;
  for (int i = t; i < 4096; i += 256){
    float f = fabsf(bfbits(u[i]));
    if (f != f) f = 1e30f;
    m = fmaxf(m, f);
  }
  red[t] = m; __syncthreads();
  for (int s = 128; s; s >>= 1){ if (t < s) red[t] = fmaxf(red[t], red[t+s]); __syncthreads(); }
  if (t == 0) *flag = (red[0] < 2.0f) ? 1 : 0;
}

// ---------- 0b. xyz -> f32 SoA ----------
__global__ __launch_bounds__(256) void cvtxyz_k(const void* __restrict__ xyz,
    const int* __restrict__ flag, float* __restrict__ X, float* __restrict__ Y,
    float* __restrict__ Z){
  const int e = blockIdx.x*256 + threadIdx.x;       // < 786432
  const int isb = *flag;
  float v = ldf(xyz, e, isb);
  int b = e / (NPT*3), r = e - b*(NPT*3), i = r/3, c = r - i*3;
  float* P = (c==0) ? X : ((c==1) ? Y : Z);
  P[b*NPT + i] = v;
}

// ---------- 0c. W -> bf16 [288][296] + BN scale/shift ----------
__global__ __launch_bounds__(256) void cvtw_k(const void* __restrict__ W,
    const void* __restrict__ g, const void* __restrict__ bb,
    const void* __restrict__ m, const void* __restrict__ v,
    const int* __restrict__ flag, __hip_bfloat16* __restrict__ Wbf,
    float* __restrict__ scale, float* __restrict__ shift, int Kin){
  const int isb = *flag;
  const int idx = blockIdx.x*256 + threadIdx.x;
  if (idx < 288*296){
    int o = idx / 296, k = idx - o*296;
    float val = (k < Kin) ? ldf(W, (long)o*Kin + k, isb) : 0.f;
    Wbf[idx] = __float2bfloat16(val);
  }
  if (idx < 288){
    float sc = ldf(g, idx, isb) * rsqrtf(ldf(v, idx, isb) + 1e-5f);
    scale[idx] = sc;
    shift[idx] = ldf(bb, idx, isb) - ldf(m, idx, isb)*sc;
  }
}

// ---------- 0d. Morton bucket sort (per batch): spatial clustering for FPS pruning ----------
// Any permutation is valid: fps uses I2 (original indices) for exact argmax tiebreak.
__global__ __launch_bounds__(1024) void sort_k(const float* __restrict__ X,
    const float* __restrict__ Y, const float* __restrict__ Z,
    float* __restrict__ X2, float* __restrict__ Y2, float* __restrict__ Z2,
    int* __restrict__ I2){
  __shared__ int hist[4096];
  __shared__ int wtot[16];
  const int b = blockIdx.x, t = threadIdx.x, base = b*NPT;
  for (int j = t; j < 4096; j += 1024) hist[j] = 0;
  __syncthreads();
  int cell[16]; float lx[16], ly[16], lz[16];
  #pragma unroll
  for (int i=0;i<16;i++){
    const int id = t + i*1024;
    float x = X[base+id], y = Y[base+id], z = Z[base+id];
    lx[i]=x; ly[i]=y; lz[i]=z;
    int cx = (int)(x*16.f); cx = cx<0?0:(cx>15?15:cx);
    int cy = (int)(y*16.f); cy = cy<0?0:(cy>15?15:cy);
    int cz = (int)(z*16.f); cz = cz<0?0:(cz>15?15:cz);
    cell[i] = (int)(spread4((unsigned)cx) | (spread4((unsigned)cy)<<1) | (spread4((unsigned)cz)<<2));
    atomicAdd(&hist[cell[i]], 1);
  }
  __syncthreads();
  // exclusive scan over 4096 bins (4 bins/thread)
  int s0 = hist[t*4], s1 = hist[t*4+1], s2 = hist[t*4+2], s3 = hist[t*4+3];
  int ls = s0+s1+s2+s3;
  int sc = ls;
  #pragma unroll
  for (int off=1; off<64; off<<=1){
    int o = __shfl_up(sc, off, 64);
    if ((t&63) >= off) sc += o;
  }
  if ((t&63) == 63) wtot[t>>6] = sc;
  __syncthreads();
  int wpre = 0;
  #pragma unroll
  for (int w=0; w<16; w++) wpre += (w < (t>>6)) ? wtot[w] : 0;
  const int ebase = wpre + sc - ls;
  hist[t*4]   = ebase;
  hist[t*4+1] = ebase + s0;
  hist[t*4+2] = ebase + s0 + s1;
  hist[t*4+3] = ebase + s0 + s1 + s2;
  __syncthreads();
  #pragma unroll
  for (int i=0;i<16;i++){
    const int dst = atomicAdd(&hist[cell[i]], 1);
    X2[base+dst] = lx[i]; Y2[base+dst] = ly[i]; Z2[base+dst] = lz[i];
    I2[base+dst] = t + i*1024;
  }
}

// ---------- 1. FPS with bit-exact bbox pruning ----------
// Each of 16 waves owns a Morton-contiguous 1024-pt chunk (tight bbox).
// Skip the update iff lb(center,bbox)*0.9999 > wavemax: then every d2 > dist[i]
// provably (margin >> fp rounding), so fminf is a bitwise no-op and the wave's
// cached best key is still exact. Key lo-word = 16383-origidx -> exact
// first-index argmax tiebreak in ORIGINAL ordering.
__global__ __launch_bounds__(1024) __attribute__((amdgpu_waves_per_eu(4,4)))
void fps_k(const float* __restrict__ X, const float* __restrict__ Y,
    const float* __restrict__ Z,
    const float* __restrict__ X2, const float* __restrict__ Y2,
    const float* __restrict__ Z2, const int* __restrict__ I2,
    const int* __restrict__ flag, float* __restrict__ nxyz, void* __restrict__ dout){
  #pragma clang fp contract(off)
  const int b = blockIdx.x, t = threadIdx.x;
  const int base = b*NPT;
  const int lane = t & 63, wid = t >> 6;
  float px[16], py[16], pz[16], dist[16];
  unsigned int li[16];
  const int p0 = base + wid*1024 + lane;
  #pragma unroll
  for (int i=0;i<16;i++){
    px[i] = X2[p0 + i*64];
    py[i] = Y2[p0 + i*64];
    pz[i] = Z2[p0 + i*64];
    li[i] = 16383u - (unsigned)I2[p0 + i*64];
    dist[i] = 1e10f;
  }
  // wave bbox (uniform after butterfly)
  float bxn=px[0],bxx=px[0],byn=py[0],byx=py[0],bzn=pz[0],bzx=pz[0];
  #pragma unroll
  for (int i=1;i<16;i++){
    bxn=fminf(bxn,px[i]); bxx=fmaxf(bxx,px[i]);
    byn=fminf(byn,py[i]); byx=fmaxf(byx,py[i]);
    bzn=fminf(bzn,pz[i]); bzx=fmaxf(bzx,pz[i]);
  }
  #pragma unroll
  for (int off=32; off; off>>=1){
    bxn=fminf(bxn,__shfl_xor(bxn,off,64)); bxx=fmaxf(bxx,__shfl_xor(bxx,off,64));
    byn=fminf(byn,__shfl_xor(byn,off,64)); byx=fmaxf(byx,__shfl_xor(byx,off,64));
    bzn=fminf(bzn,__shfl_xor(bzn,off,64)); bzx=fmaxf(bzx,__shfl_xor(bzx,off,64));
  }
  __shared__ unsigned long long slot[2][16];
  __shared__ float ox[SP], oy[SP], oz[SP];
  __shared__ int   oi[SP];
  float cx = X[base], cy = Y[base], cz = Z[base];
  int cur = 0;
  unsigned long long wkey = 0ull;
  float wavemax = 1e30f;
  for (int it=0; it<SP; it++){
    if (t == 0){ ox[it]=cx; oy[it]=cy; oz[it]=cz; oi[it]=cur; }
    // conservative lower bound of d2(center, any point in this wave's bbox)
    float ddx = fmaxf(fmaxf(bxn-cx, cx-bxx), 0.f);
    float ddy = fmaxf(fmaxf(byn-cy, cy-byx), 0.f);
    float ddz = fmaxf(fmaxf(bzn-cz, cz-bzx), 0.f);
    float lb = ddx*ddx + ddy*ddy + ddz*ddz;
    if (!(lb * 0.9999f > wavemax)){
      unsigned long long best = 0ull;
      #pragma unroll
      for (int i=0;i<16;i++){
        float dx = px[i]-cx, dy = py[i]-cy, dz = pz[i]-cz;
        float d2 = dx*dx + dy*dy; d2 = d2 + dz*dz;
        float dn = fminf(dist[i], d2); dist[i] = dn;
        unsigned long long key = ((unsigned long long)__float_as_uint(dn) << 32)
                               | (unsigned long long)li[i];
        best = (key > best) ? key : best;
      }
      #pragma unroll
      for (int off=32; off; off>>=1){
        unsigned long long o = __shfl_xor(best, off, 64);
        best = (o > best) ? o : best;
      }
      wkey = best;
      wavemax = __uint_as_float((unsigned)(best >> 32));
    }
    const int p = it & 1;
    if (lane == 0) slot[p][wid] = wkey;
    __syncthreads();
    // lane-parallel 16-slot reduce: 1 ds_read + 4 shfl levels
    unsigned long long g = slot[p][lane & 15];
    #pragma unroll
    for (int m=8; m; m>>=1){
      unsigned long long o = __shfl_xor(g, m, 64);
      g = (o > g) ? o : g;
    }
    cur = 16383 - (int)(unsigned)g;
    cur = __builtin_amdgcn_readfirstlane(cur);
    cx = X[base+cur]; cy = Y[base+cur]; cz = Z[base+cur];
  }
  __syncthreads();
  if (t < SP){
    const int isb = *flag;
    const long bs = (long)b*SP + t;
    float fx=ox[t], fy=oy[t], fz=oz[t]; int ii=oi[t];
    nxyz[bs*3+0]=fx; nxyz[bs*3+1]=fy; nxyz[bs*3+2]=fz;
    sto(dout, bs*3+0, fx, isb);
    sto(dout, bs*3+1, fy, isb);
    sto(dout, bs*3+2, fz, isb);
    sto(dout, OFF_IND + bs, (float)ii, isb);
  }
}

// ---------- 2. ball query (SoA f32) ----------
__global__ __launch_bounds__(256) void ballq_k(const float* __restrict__ X,
    const float* __restrict__ Y, const float* __restrict__ Z,
    const float* __restrict__ nxyz, int* __restrict__ bidx){
  #pragma clang fp contract(off)
  const int gw = (blockIdx.x*256 + threadIdx.x) >> 6;
  const int lane = threadIdx.x & 63;
  const int b = gw >> 8, base = b*NPT;
  const float cx = nxyz[gw*3+0], cy = nxyz[gw*3+1], cz = nxyz[gw*3+2];
  int cnt = 0, first = 0; bool havef = false;
  for (int st = 0; st < NPT && cnt < KS; st += 64){
    const int id = st + lane;
    float dx = X[base+id]-cx, dy = Y[base+id]-cy, dz = Z[base+id]-cz;
    float d2 = dx*dx + dy*dy; d2 = d2 + dz*dz;
    unsigned long long mk = __ballot(d2 <= 0.09f);  // == (f32 d2 < double 0.09)
    if (mk){
      if (!havef){ first = st + __builtin_ctzll(mk); havef = true; }
      int rank = cnt + __popcll(mk & ((1ull<<lane)-1ull));
      if (((mk>>lane)&1ull) && rank < KS) bidx[gw*KS + rank] = id;
      cnt += __popcll(mk);
    }
  }
  if (cnt < KS && lane >= cnt && lane < KS) bidx[gw*KS + lane] = first;
}

// ---------- 3. gather -> h0 [n][296] bf16 via LDS tile ----------
__global__ __launch_bounds__(256) void gather_k(const void* __restrict__ xyz,
    const void* __restrict__ feat, const int* __restrict__ flag,
    const int* __restrict__ bidx, const float* __restrict__ nxyz,
    __hip_bfloat16* __restrict__ h0){
  __shared__ __hip_bfloat16 tile[64*296];
  const int isb = *flag;
  const int t = threadIdx.x, n0 = blockIdx.x*64;
  const int nl = t >> 2, cg = t & 3;
  const int n = n0 + nl, b = n >> 12, s = n >> 4;
  const int id = bidx[n];
  for (int j=0; j<74; j++){
    int c = cg*74 + j;
    float vv = 0.f;
    if (c < 3)       vv = (ldf(xyz, ((long)b*NPT + id)*3 + c, isb) - nxyz[(long)s*3 + c]) / 0.3f;
    else if (c < 291) vv = ldf(feat, ((long)b*CH + (c-3))*(long)NPT + id, isb);
    tile[nl*296 + c] = __float2bfloat16(vv);
  }
  __syncthreads();
  const uint4* src = (const uint4*)tile;
  uint4* dst = (uint4*)((char*)h0 + (long)n0*592);
  for (int j = t; j < 2368; j += 256) dst[j] = src[j];
}

// ---------- 4. MFMA GEMM: Out[n][o] = relu(BN(sum_k A[n][k]*W[o][k])) ----------
// Block tile 128n x 96o, whole-K A-tile in LDS (global_load_lds), W frags from L2.
__global__ __launch_bounds__(256, 2) void gemm_k(
    const __hip_bfloat16* __restrict__ A, int astr,
    const __hip_bfloat16* __restrict__ W,
    const float* __restrict__ scale, const float* __restrict__ shift,
    __hip_bfloat16* __restrict__ Out, int ostr,
    int ktiles, int kvalid){
  extern __shared__ char lds[];
  const int t = threadIdx.x, lane = t & 63, wid = t >> 6;
  const int wm = wid & 1, wo = wid >> 1;
  const int bx = blockIdx.x, by = blockIdx.y;
  {
    const char* src = (const char*)(A + (long)bx*128*astr);
    const int chunks = (128*astr*2) >> 10;
    for (int c = wid; c < chunks; c += 4)
      gload_lds(src + c*1024 + lane*16, lds + c*1024);
  }
  f32x4 acc[4][3];
  #pragma unroll
  for (int mf=0; mf<4; mf++)
    #pragma unroll
    for (int of=0; of<3; of++) acc[mf][of] = (f32x4){0.f,0.f,0.f,0.f};

  const int mrow  = wm*64 + (lane & 15);
  const int kg    = (lane >> 4) * 8;
  const int obase = by*96 + wo*48 + (lane & 15);
  __syncthreads();

  for (int kt = 0; kt < ktiles; kt++){
    const int k0 = kt*32 + kg;
    const bool z = (k0 >= kvalid);
    const int k0c = z ? 0 : k0;
    bf16x8 a[4], bf[3];
    #pragma unroll
    for (int mf=0; mf<4; mf++)
      a[mf] = *(const bf16x8*)(lds + ((long)(mrow + mf*16)*astr + k0c)*2);
    if (z){
      bf16x8 zz = {0,0,0,0,0,0,0,0};
      #pragma unroll
      for (int mf=0; mf<4; mf++) a[mf] = zz;
    }
    #pragma unroll
    for (int of=0; of<3; of++)
      bf[of] = *(const bf16x8*)(W + (long)(obase + of*16)*296 + k0c);
    #pragma unroll
    for (int mf=0; mf<4; mf++)
      #pragma unroll
      for (int of=0; of<3; of++)
        acc[mf][of] = __builtin_amdgcn_mfma_f32_16x16x32_bf16(a[mf], bf[of], acc[mf][of], 0, 0, 0);
  }

  float sc[3], sh[3];
  #pragma unroll
  for (int of=0; of<3; of++){ sc[of] = scale[obase + of*16]; sh[of] = shift[obase + of*16]; }
  #pragma unroll
  for (int mf=0; mf<4; mf++)
    #pragma unroll
    for (int of=0; of<3; of++)
      #pragma unroll
      for (int r=0; r<4; r++){
        const long row = (long)bx*128 + wm*64 + mf*16 + (lane>>4)*4 + r;
        const int o = obase + of*16;
        float vv = acc[mf][of][r]*sc[of] + sh[of];
        Out[row*ostr + o] = __float2bfloat16(fmaxf(vv, 0.f));
      }
}

// ---------- 5. maxpool over k: h[n][288] -> out[b][o][s] ----------
__global__ __launch_bounds__(256) void maxk_k(const __hip_bfloat16* __restrict__ h,
    const int* __restrict__ flag, void* __restrict__ dout){
  __shared__ __hip_bfloat16 tile[128*288];
  const int isb = *flag;
  const int t = threadIdx.x;
  const int b = blockIdx.x >> 5, s0 = (blockIdx.x & 31)*8;
  const long n0 = (long)b*4096 + (long)s0*16;
  {
    const char* src = (const char*)(h + n0*288);
    for (int c = (t>>6); c < 72; c += 4)
      gload_lds(src + c*1024 + (t&63)*16, (char*)tile + c*1024);
  }
  __syncthreads();
  for (int o = t; o < 288; o += 256){
    float mx[8];
    #pragma unroll
    for (int sl=0; sl<8; sl++){
      float m = -1e30f;
      #pragma unroll
      for (int kk=0; kk<16; kk++)
        m = fmaxf(m, __bfloat162float(tile[(sl*16 + kk)*288 + o]));
      mx[sl] = m;
    }
    const long e0 = OFF_FEAT + (long)b*73728 + (long)o*256 + s0;
    if (isb){
      unsigned short u[8];
      #pragma unroll
      for (int sl=0; sl<8; sl++){
        __hip_bfloat16 hb = __float2bfloat16(mx[sl]);
        __builtin_memcpy(&u[sl], &hb, 2);
      }
      uint4 pk; __builtin_memcpy(&pk, u, 16);
      *(uint4*)((__hip_bfloat16*)dout + e0) = pk;
    } else {
      float* fo = (float*)dout + e0;
      *(float4*)fo     = make_float4(mx[0],mx[1],mx[2],mx[3]);
      *(float4*)(fo+4) = make_float4(mx[4],mx[5],mx[6],mx[7]);
    }
  }
}

extern "C" void kernel_launch(void* const* d_in, const int* in_sizes, int n_in,
                              void* d_out, int out_size, void* d_ws, size_t ws_size,
                              hipStream_t stream){
  const void* xyz  = d_in[0];
  const void* feat = d_in[1];
  const void* W0 = d_in[2];  const void* g0 = d_in[3];  const void* b0 = d_in[4];
  const void* m0 = d_in[5];  const void* v0 = d_in[6];
  const void* W1 = d_in[7];  const void* g1 = d_in[8];  const void* b1 = d_in[9];
  const void* m1 = d_in[10]; const void* v1 = d_in[11];
  const void* W2 = d_in[12]; const void* g2 = d_in[13]; const void* b2 = d_in[14];
  const void* m2 = d_in[15]; const void* v2 = d_in[16];

  char* ws = (char*)d_ws;
  int*   flag  = (int*)ws;                                   // [0,64)
  float* sc0   = (float*)(ws + 64);                          // 3x(288+288) f32
  float* sh0   = sc0 + 288;
  float* sc1   = sc0 + 576;  float* sh1 = sc0 + 864;
  float* sc2   = sc0 + 1152; float* sh2 = sc0 + 1440;
  __hip_bfloat16* Wb0 = (__hip_bfloat16*)(ws + 7040);        // 288*296*2 = 170496
  __hip_bfloat16* Wb1 = Wb0 + 288*296;
  __hip_bfloat16* Wb2 = Wb1 + 288*296;                       // ends @ 518528
  float* nxyz = (float*)(ws + 518656);                       // 49152 -> 567808
  int*   bidx = (int*)(ws + 567808);                         // 262144 -> 829952
  float* X    = (float*)(ws + 1048576);                      // overlaid with bufA (dead after ballq)
  float* Y    = X + NBAT*NPT;
  float* Z    = Y + NBAT*NPT;
  __hip_bfloat16* bufA = (__hip_bfloat16*)(ws + 1048576);    // [65536][296] = 38797312
  __hip_bfloat16* bufB = (__hip_bfloat16*)(ws + 1048576 + 38797312); // [65536][288] -> end 77594624
  // Morton-sorted copies, overlaid on bufB (dead before gemm#1 writes bufB)
  float* X2 = (float*)bufB;
  float* Y2 = X2 + NBAT*NPT;
  float* Z2 = Y2 + NBAT*NPT;
  int*   I2 = (int*)(Z2 + NBAT*NPT);                         // 4 MiB total << 37 MiB

  detect_k<<<1, 256, 0, stream>>>(xyz, flag);
  cvtxyz_k<<<3072, 256, 0, stream>>>(xyz, flag, X, Y, Z);
  cvtw_k<<<333, 256, 0, stream>>>(W0, g0, b0, m0, v0, flag, Wb0, sc0, sh0, 291);
  cvtw_k<<<333, 256, 0, stream>>>(W1, g1, b1, m1, v1, flag, Wb1, sc1, sh1, 288);
  cvtw_k<<<333, 256, 0, stream>>>(W2, g2, b2, m2, v2, flag, Wb2, sc2, sh2, 288);
  sort_k<<<NBAT, 1024, 0, stream>>>(X, Y, Z, X2, Y2, Z2, I2);
  fps_k<<<NBAT, 1024, 0, stream>>>(X, Y, Z, X2, Y2, Z2, I2, flag, nxyz, d_out);
  ballq_k<<<1024, 256, 0, stream>>>(X, Y, Z, nxyz, bidx);
  gather_k<<<1024, 256, 0, stream>>>(xyz, feat, flag, bidx, nxyz, bufA);
  gemm_k<<<dim3(512,3), 256, 128*296*2, stream>>>(bufA, 296, Wb0, sc0, sh0, bufB, 288, 10, 296);
  gemm_k<<<dim3(512,3), 256, 128*288*2, stream>>>(bufB, 288, Wb1, sc1, sh1, bufA, 296, 9, 288);
  gemm_k<<<dim3(512,3), 256, 128*296*2, stream>>>(bufA, 296, Wb2, sc2, sh2, bufB, 288, 9, 288);
  maxk_k<<<512, 256, 0, stream>>>(bufB, flag, d_out);
}

// Round 3
// 1009.120 us; speedup vs baseline: 1.2580x; 1.0033x over previous
//
#include <hip/hip_runtime.h>
#include <hip/hip_bf16.h>
#include <string.h>

#define NPT   16384
#define NBAT  16
#define CH    288
#define SP    256
#define KS    16
#define OFF_FEAT 12288L
#define OFF_IND  1191936L

// ---------- helpers ----------
__device__ __forceinline__ float bfbits(unsigned short u){
  unsigned int x = ((unsigned int)u) << 16; float f; __builtin_memcpy(&f,&x,4); return f;
}
__device__ __forceinline__ float ldf(const void* p, long i, int isb){
  if (isb) return __bfloat162float(((const __hip_bfloat16*)p)[i]);
  return ((const float*)p)[i];
}
__device__ __forceinline__ void sto(void* p, long i, float v, int isb){
  if (isb) ((__hip_bfloat16*)p)[i] = __float2bfloat16(v);
  else     ((float*)p)[i] = v;
}
__device__ __forceinline__ void gload_lds(const void* g, void* l){
  __builtin_amdgcn_global_load_lds((const __attribute__((address_space(1))) void*)g,
      (__attribute__((address_space(3))) void*)l, 16, 0, 0);
}
__device__ __forceinline__ unsigned spread4(unsigned x){
  return (x&1u) | ((x&2u)<<2) | ((x&4u)<<4) | ((x&8u)<<6);
}

typedef __attribute__((ext_vector_type(8))) short bf16x8;
typedef __attribute__((ext_vector_type(4))) float f32x4;
typedef __attribute__((ext_vector_type(2))) float f32x2;

// ---------- 0. input dtype detection ----------
__global__ void detect_k(const void* __restrict__ xyz, int* __restrict__ flag){
  __shared__ float red[256];
  const int t = threadIdx.x;
  const unsigned short* u = (const unsigned short*)xyz;
  float m = 0.f;
  for (int i = t; i < 4096; i += 256){
    float f = fabsf(bfbits(u[i]));
    if (f != f) f = 1e30f;
    m = fmaxf(m, f);
  }
  red[t] = m; __syncthreads();
  for (int s = 128; s; s >>= 1){ if (t < s) red[t] = fmaxf(red[t], red[t+s]); __syncthreads(); }
  if (t == 0) *flag = (red[0] < 2.0f) ? 1 : 0;
}

// ---------- 0b. xyz -> f32 SoA + interleaved float4 (for fps center loads) ----------
__global__ __launch_bounds__(256) void cvtxyz_k(const void* __restrict__ xyz,
    const int* __restrict__ flag, float* __restrict__ X, float* __restrict__ Y,
    float* __restrict__ Z, float4* __restrict__ P4){
  const int n = blockIdx.x*256 + threadIdx.x;       // < 262144 points
  const int isb = *flag;
  float x = ldf(xyz, (long)n*3+0, isb);
  float y = ldf(xyz, (long)n*3+1, isb);
  float z = ldf(xyz, (long)n*3+2, isb);
  X[n] = x; Y[n] = y; Z[n] = z;                     // n == b*NPT+i (NPT=2^14)
  P4[n] = make_float4(x, y, z, 0.f);
}

// ---------- 0c. W -> bf16 [288][296] + BN scale/shift ----------
__global__ __launch_bounds__(256) void cvtw_k(const void* __restrict__ W,
    const void* __restrict__ g, const void* __restrict__ bb,
    const void* __restrict__ m, const void* __restrict__ v,
    const int* __restrict__ flag, __hip_bfloat16* __restrict__ Wbf,
    float* __restrict__ scale, float* __restrict__ shift, int Kin){
  const int isb = *flag;
  const int idx = blockIdx.x*256 + threadIdx.x;
  if (idx < 288*296){
    int o = idx / 296, k = idx - o*296;
    float val = (k < Kin) ? ldf(W, (long)o*Kin + k, isb) : 0.f;
    Wbf[idx] = __float2bfloat16(val);
  }
  if (idx < 288){
    float sc = ldf(g, idx, isb) * rsqrtf(ldf(v, idx, isb) + 1e-5f);
    scale[idx] = sc;
    shift[idx] = ldf(bb, idx, isb) - ldf(m, idx, isb)*sc;
  }
}

// ---------- 0d. Morton bucket sort (per batch): spatial clustering for FPS pruning ----------
// Any permutation is valid: fps uses I2 (original indices) for exact argmax tiebreak.
__global__ __launch_bounds__(1024) void sort_k(const float* __restrict__ X,
    const float* __restrict__ Y, const float* __restrict__ Z,
    float* __restrict__ X2, float* __restrict__ Y2, float* __restrict__ Z2,
    int* __restrict__ I2){
  __shared__ int hist[4096];
  __shared__ int wtot[16];
  const int b = blockIdx.x, t = threadIdx.x, base = b*NPT;
  for (int j = t; j < 4096; j += 1024) hist[j] = 0;
  __syncthreads();
  int cell[16]; float lx[16], ly[16], lz[16];
  #pragma unroll
  for (int i=0;i<16;i++){
    const int id = t + i*1024;
    float x = X[base+id], y = Y[base+id], z = Z[base+id];
    lx[i]=x; ly[i]=y; lz[i]=z;
    int cx = (int)(x*16.f); cx = cx<0?0:(cx>15?15:cx);
    int cy = (int)(y*16.f); cy = cy<0?0:(cy>15?15:cy);
    int cz = (int)(z*16.f); cz = cz<0?0:(cz>15?15:cz);
    cell[i] = (int)(spread4((unsigned)cx) | (spread4((unsigned)cy)<<1) | (spread4((unsigned)cz)<<2));
    atomicAdd(&hist[cell[i]], 1);
  }
  __syncthreads();
  // exclusive scan over 4096 bins (4 bins/thread)
  int s0 = hist[t*4], s1 = hist[t*4+1], s2 = hist[t*4+2], s3 = hist[t*4+3];
  int ls = s0+s1+s2+s3;
  int sc = ls;
  #pragma unroll
  for (int off=1; off<64; off<<=1){
    int o = __shfl_up(sc, off, 64);
    if ((t&63) >= off) sc += o;
  }
  if ((t&63) == 63) wtot[t>>6] = sc;
  __syncthreads();
  int wpre = 0;
  #pragma unroll
  for (int w=0; w<16; w++) wpre += (w < (t>>6)) ? wtot[w] : 0;
  const int ebase = wpre + sc - ls;
  hist[t*4]   = ebase;
  hist[t*4+1] = ebase + s0;
  hist[t*4+2] = ebase + s0 + s1;
  hist[t*4+3] = ebase + s0 + s1 + s2;
  __syncthreads();
  #pragma unroll
  for (int i=0;i<16;i++){
    const int dst = atomicAdd(&hist[cell[i]], 1);
    X2[base+dst] = lx[i]; Y2[base+dst] = ly[i]; Z2[base+dst] = lz[i];
    I2[base+dst] = t + i*1024;
  }
}

// ---------- 1. FPS: packed-f32 update + bit-exact bbox pruning ----------
// Distance math on f32x2 (v_pk_add/mul_f32), per-element op order IDENTICAL to the
// scalar version ((dx*dx+dy*dy)+dz*dz, contract off, minnum) -> bit-identical dists.
// Prune: skip update iff lb(center,bbox)*0.9999 > wavemax (margin >> fp rounding of
// the bound chain, so fminf is provably a bitwise no-op for every point).
// Key lo-word = 16383-origidx -> exact first-index argmax tiebreak in ORIGINAL order.
__global__ __launch_bounds__(1024) __attribute__((amdgpu_waves_per_eu(4,4)))
void fps_k(const float4* __restrict__ P4,
    const float* __restrict__ X2, const float* __restrict__ Y2,
    const float* __restrict__ Z2, const int* __restrict__ I2,
    const int* __restrict__ flag, float* __restrict__ nxyz, void* __restrict__ dout){
  #pragma clang fp contract(off)
  const int b = blockIdx.x, t = threadIdx.x;
  const int base = b*NPT;
  const int lane = t & 63, wid = t >> 6;
  f32x2 px[8], py[8], pz[8], ds[8];
  unsigned li[16];
  const int p0 = base + wid*1024 + lane;
  #pragma unroll
  for (int j=0;j<8;j++){
    px[j] = (f32x2){X2[p0 + (2*j)*64], X2[p0 + (2*j+1)*64]};
    py[j] = (f32x2){Y2[p0 + (2*j)*64], Y2[p0 + (2*j+1)*64]};
    pz[j] = (f32x2){Z2[p0 + (2*j)*64], Z2[p0 + (2*j+1)*64]};
    li[2*j]   = 16383u - (unsigned)I2[p0 + (2*j)*64];
    li[2*j+1] = 16383u - (unsigned)I2[p0 + (2*j+1)*64];
    ds[j] = (f32x2){1e10f, 1e10f};
  }
  // wave bbox (uniform after butterfly)
  float bxn=px[0].x,bxx=px[0].x,byn=py[0].x,byx=py[0].x,bzn=pz[0].x,bzx=pz[0].x;
  #pragma unroll
  for (int j=0;j<8;j++){
    bxn=fminf(bxn,fminf(px[j].x,px[j].y)); bxx=fmaxf(bxx,fmaxf(px[j].x,px[j].y));
    byn=fminf(byn,fminf(py[j].x,py[j].y)); byx=fmaxf(byx,fmaxf(py[j].x,py[j].y));
    bzn=fminf(bzn,fminf(pz[j].x,pz[j].y)); bzx=fmaxf(bzx,fmaxf(pz[j].x,pz[j].y));
  }
  #pragma unroll
  for (int off=32; off; off>>=1){
    bxn=fminf(bxn,__shfl_xor(bxn,off,64)); bxx=fmaxf(bxx,__shfl_xor(bxx,off,64));
    byn=fminf(byn,__shfl_xor(byn,off,64)); byx=fmaxf(byx,__shfl_xor(byx,off,64));
    bzn=fminf(bzn,__shfl_xor(bzn,off,64)); bzx=fmaxf(bzx,__shfl_xor(bzx,off,64));
  }
  __shared__ unsigned long long slot[2][16];
  __shared__ float ox[SP], oy[SP], oz[SP];
  __shared__ int   oi[SP];
  float4 c4 = P4[base];
  float cx = c4.x, cy = c4.y, cz = c4.z;
  int cur = 0;
  unsigned long long wkey = 0ull;
  float wavemax = 1e30f;
  for (int it=0; it<SP; it++){
    if (t == 0){ ox[it]=cx; oy[it]=cy; oz[it]=cz; oi[it]=cur; }
    // conservative lower bound of d2(center, any point in this wave's bbox)
    float ddx = fmaxf(fmaxf(bxn-cx, cx-bxx), 0.f);
    float ddy = fmaxf(fmaxf(byn-cy, cy-byx), 0.f);
    float ddz = fmaxf(fmaxf(bzn-cz, cz-bzx), 0.f);
    float lb = ddx*ddx + ddy*ddy + ddz*ddz;
    if (!(lb * 0.9999f > wavemax)){
      const f32x2 Cx = {cx,cx}, Cy = {cy,cy}, Cz = {cz,cz};
      unsigned long long best = 0ull;
      #pragma unroll
      for (int j=0;j<8;j++){
        f32x2 dx = px[j]-Cx, dy = py[j]-Cy, dz = pz[j]-Cz;
        f32x2 m0 = dx*dx, m1 = dy*dy, m2 = dz*dz;
        f32x2 d2 = (m0+m1)+m2;
        f32x2 dn = __builtin_elementwise_min(ds[j], d2);
        ds[j] = dn;
        unsigned long long k0 = ((unsigned long long)__float_as_uint(dn.x)<<32)
                              | (unsigned long long)li[2*j];
        unsigned long long k1 = ((unsigned long long)__float_as_uint(dn.y)<<32)
                              | (unsigned long long)li[2*j+1];
        best = (k0 > best) ? k0 : best;
        best = (k1 > best) ? k1 : best;
      }
      #pragma unroll
      for (int off=32; off; off>>=1){
        unsigned long long o = __shfl_xor(best, off, 64);
        best = (o > best) ? o : best;
      }
      wkey = best;
      wavemax = __uint_as_float((unsigned)(best >> 32));
    }
    const int p = it & 1;
    if (lane == 0) slot[p][wid] = wkey;
    __syncthreads();
    // lane-parallel 16-slot reduce: 1 ds_read + 4 shfl levels
    unsigned long long g = slot[p][lane & 15];
    #pragma unroll
    for (int m=8; m; m>>=1){
      unsigned long long o = __shfl_xor(g, m, 64);
      g = (o > g) ? o : g;
    }
    cur = 16383 - (int)(unsigned)g;
    cur = __builtin_amdgcn_readfirstlane(cur);
    c4 = P4[base+cur];
    cx = c4.x; cy = c4.y; cz = c4.z;
  }
  __syncthreads();
  if (t < SP){
    const int isb = *flag;
    const long bs = (long)b*SP + t;
    float fx=ox[t], fy=oy[t], fz=oz[t]; int ii=oi[t];
    nxyz[bs*3+0]=fx; nxyz[bs*3+1]=fy; nxyz[bs*3+2]=fz;
    sto(dout, bs*3+0, fx, isb);
    sto(dout, bs*3+1, fy, isb);
    sto(dout, bs*3+2, fz, isb);
    sto(dout, OFF_IND + bs, (float)ii, isb);
  }
}

// ---------- 2. ball query (SoA f32) ----------
__global__ __launch_bounds__(256) void ballq_k(const float* __restrict__ X,
    const float* __restrict__ Y, const float* __restrict__ Z,
    const float* __restrict__ nxyz, int* __restrict__ bidx){
  #pragma clang fp contract(off)
  const int gw = (blockIdx.x*256 + threadIdx.x) >> 6;
  const int lane = threadIdx.x & 63;
  const int b = gw >> 8, base = b*NPT;
  const float cx = nxyz[gw*3+0], cy = nxyz[gw*3+1], cz = nxyz[gw*3+2];
  int cnt = 0, first = 0; bool havef = false;
  for (int st = 0; st < NPT && cnt < KS; st += 64){
    const int id = st + lane;
    float dx = X[base+id]-cx, dy = Y[base+id]-cy, dz = Z[base+id]-cz;
    float d2 = dx*dx + dy*dy; d2 = d2 + dz*dz;
    unsigned long long mk = __ballot(d2 <= 0.09f);  // == (f32 d2 < double 0.09)
    if (mk){
      if (!havef){ first = st + __builtin_ctzll(mk); havef = true; }
      int rank = cnt + __popcll(mk & ((1ull<<lane)-1ull));
      if (((mk>>lane)&1ull) && rank < KS) bidx[gw*KS + rank] = id;
      cnt += __popcll(mk);
    }
  }
  if (cnt < KS && lane >= cnt && lane < KS) bidx[gw*KS + lane] = first;
}

// ---------- 3. gather -> h0 [n][296] bf16 via LDS tile ----------
__global__ __launch_bounds__(256) void gather_k(const void* __restrict__ xyz,
    const void* __restrict__ feat, const int* __restrict__ flag,
    const int* __restrict__ bidx, const float* __restrict__ nxyz,
    __hip_bfloat16* __restrict__ h0){
  __shared__ __hip_bfloat16 tile[64*296];
  const int isb = *flag;
  const int t = threadIdx.x, n0 = blockIdx.x*64;
  const int nl = t >> 2, cg = t & 3;
  const int n = n0 + nl, b = n >> 12, s = n >> 4;
  const int id = bidx[n];
  for (int j=0; j<74; j++){
    int c = cg*74 + j;
    float vv = 0.f;
    if (c < 3)       vv = (ldf(xyz, ((long)b*NPT + id)*3 + c, isb) - nxyz[(long)s*3 + c]) / 0.3f;
    else if (c < 291) vv = ldf(feat, ((long)b*CH + (c-3))*(long)NPT + id, isb);
    tile[nl*296 + c] = __float2bfloat16(vv);
  }
  __syncthreads();
  const uint4* src = (const uint4*)tile;
  uint4* dst = (uint4*)((char*)h0 + (long)n0*592);
  for (int j = t; j < 2368; j += 256) dst[j] = src[j];
}

// ---------- 4. MFMA GEMM: Out[n][o] = relu(BN(sum_k A[n][k]*W[o][k])) ----------
// Block tile 128n x 96o, whole-K A-tile in LDS (global_load_lds), W frags from L2.
__global__ __launch_bounds__(256, 2) void gemm_k(
    const __hip_bfloat16* __restrict__ A, int astr,
    const __hip_bfloat16* __restrict__ W,
    const float* __restrict__ scale, const float* __restrict__ shift,
    __hip_bfloat16* __restrict__ Out, int ostr,
    int ktiles, int kvalid){
  extern __shared__ char lds[];
  const int t = threadIdx.x, lane = t & 63, wid = t >> 6;
  const int wm = wid & 1, wo = wid >> 1;
  const int bx = blockIdx.x, by = blockIdx.y;
  {
    const char* src = (const char*)(A + (long)bx*128*astr);
    const int chunks = (128*astr*2) >> 10;
    for (int c = wid; c < chunks; c += 4)
      gload_lds(src + c*1024 + lane*16, lds + c*1024);
  }
  f32x4 acc[4][3];
  #pragma unroll
  for (int mf=0; mf<4; mf++)
    #pragma unroll
    for (int of=0; of<3; of++) acc[mf][of] = (f32x4){0.f,0.f,0.f,0.f};

  const int mrow  = wm*64 + (lane & 15);
  const int kg    = (lane >> 4) * 8;
  const int obase = by*96 + wo*48 + (lane & 15);
  __syncthreads();

  for (int kt = 0; kt < ktiles; kt++){
    const int k0 = kt*32 + kg;
    const bool z = (k0 >= kvalid);
    const int k0c = z ? 0 : k0;
    bf16x8 a[4], bf[3];
    #pragma unroll
    for (int mf=0; mf<4; mf++)
      a[mf] = *(const bf16x8*)(lds + ((long)(mrow + mf*16)*astr + k0c)*2);
    if (z){
      bf16x8 zz = {0,0,0,0,0,0,0,0};
      #pragma unroll
      for (int mf=0; mf<4; mf++) a[mf] = zz;
    }
    #pragma unroll
    for (int of=0; of<3; of++)
      bf[of] = *(const bf16x8*)(W + (long)(obase + of*16)*296 + k0c);
    #pragma unroll
    for (int mf=0; mf<4; mf++)
      #pragma unroll
      for (int of=0; of<3; of++)
        acc[mf][of] = __builtin_amdgcn_mfma_f32_16x16x32_bf16(a[mf], bf[of], acc[mf][of], 0, 0, 0);
  }

  float sc[3], sh[3];
  #pragma unroll
  for (int of=0; of<3; of++){ sc[of] = scale[obase + of*16]; sh[of] = shift[obase + of*16]; }
  #pragma unroll
  for (int mf=0; mf<4; mf++)
    #pragma unroll
    for (int of=0; of<3; of++)
      #pragma unroll
      for (int r=0; r<4; r++){
        const long row = (long)bx*128 + wm*64 + mf*16 + (lane>>4)*4 + r;
        const int o = obase + of*16;
        float vv = acc[mf][of][r]*sc[of] + sh[of];
        Out[row*ostr + o] = __float2bfloat16(fmaxf(vv, 0.f));
      }
}

// ---------- 5. maxpool over k: h[n][288] -> out[b][o][s] ----------
__global__ __launch_bounds__(256) void maxk_k(const __hip_bfloat16* __restrict__ h,
    const int* __restrict__ flag, void* __restrict__ dout){
  __shared__ __hip_bfloat16 tile[128*288];
  const int isb = *flag;
  const int t = threadIdx.x;
  const int b = blockIdx.x >> 5, s0 = (blockIdx.x & 31)*8;
  const long n0 = (long)b*4096 + (long)s0*16;
  {
    const char* src = (const char*)(h + n0*288);
    for (int c = (t>>6); c < 72; c += 4)
      gload_lds(src + c*1024 + (t&63)*16, (char*)tile + c*1024);
  }
  __syncthreads();
  for (int o = t; o < 288; o += 256){
    float mx[8];
    #pragma unroll
    for (int sl=0; sl<8; sl++){
      float m = -1e30f;
      #pragma unroll
      for (int kk=0; kk<16; kk++)
        m = fmaxf(m, __bfloat162float(tile[(sl*16 + kk)*288 + o]));
      mx[sl] = m;
    }
    const long e0 = OFF_FEAT + (long)b*73728 + (long)o*256 + s0;
    if (isb){
      unsigned short u[8];
      #pragma unroll
      for (int sl=0; sl<8; sl++){
        __hip_bfloat16 hb = __float2bfloat16(mx[sl]);
        __builtin_memcpy(&u[sl], &hb, 2);
      }
      uint4 pk; __builtin_memcpy(&pk, u, 16);
      *(uint4*)((__hip_bfloat16*)dout + e0) = pk;
    } else {
      float* fo = (float*)dout + e0;
      *(float4*)fo     = make_float4(mx[0],mx[1],mx[2],mx[3]);
      *(float4*)(fo+4) = make_float4(mx[4],mx[5],mx[6],mx[7]);
    }
  }
}

extern "C" void kernel_launch(void* const* d_in, const int* in_sizes, int n_in,
                              void* d_out, int out_size, void* d_ws, size_t ws_size,
                              hipStream_t stream){
  const void* xyz  = d_in[0];
  const void* feat = d_in[1];
  const void* W0 = d_in[2];  const void* g0 = d_in[3];  const void* b0 = d_in[4];
  const void* m0 = d_in[5];  const void* v0 = d_in[6];
  const void* W1 = d_in[7];  const void* g1 = d_in[8];  const void* b1 = d_in[9];
  const void* m1 = d_in[10]; const void* v1 = d_in[11];
  const void* W2 = d_in[12]; const void* g2 = d_in[13]; const void* b2 = d_in[14];
  const void* m2 = d_in[15]; const void* v2 = d_in[16];

  char* ws = (char*)d_ws;
  int*   flag  = (int*)ws;                                   // [0,64)
  float* sc0   = (float*)(ws + 64);                          // 3x(288+288) f32
  float* sh0   = sc0 + 288;
  float* sc1   = sc0 + 576;  float* sh1 = sc0 + 864;
  float* sc2   = sc0 + 1152; float* sh2 = sc0 + 1440;
  __hip_bfloat16* Wb0 = (__hip_bfloat16*)(ws + 7040);        // 288*296*2 = 170496
  __hip_bfloat16* Wb1 = Wb0 + 288*296;
  __hip_bfloat16* Wb2 = Wb1 + 288*296;                       // ends @ 518528
  float* nxyz = (float*)(ws + 518656);                       // 49152 -> 567808
  int*   bidx = (int*)(ws + 567808);                         // 262144 -> 829952
  float* X    = (float*)(ws + 1048576);                      // overlaid with bufA (dead after ballq)
  float* Y    = X + NBAT*NPT;
  float* Z    = Y + NBAT*NPT;
  float4* P4  = (float4*)(ws + 1048576 + 3145728);           // 4 MiB, dead after fps
  __hip_bfloat16* bufA = (__hip_bfloat16*)(ws + 1048576);    // [65536][296] = 38797312
  __hip_bfloat16* bufB = (__hip_bfloat16*)(ws + 1048576 + 38797312); // [65536][288] -> end 77594624
  // Morton-sorted copies, overlaid on bufB (dead before gemm#1 writes bufB)
  float* X2 = (float*)bufB;
  float* Y2 = X2 + NBAT*NPT;
  float* Z2 = Y2 + NBAT*NPT;
  int*   I2 = (int*)(Z2 + NBAT*NPT);                         // 4 MiB total << 37 MiB

  detect_k<<<1, 256, 0, stream>>>(xyz, flag);
  cvtxyz_k<<<1024, 256, 0, stream>>>(xyz, flag, X, Y, Z, P4);
  cvtw_k<<<333, 256, 0, stream>>>(W0, g0, b0, m0, v0, flag, Wb0, sc0, sh0, 291);
  cvtw_k<<<333, 256, 0, stream>>>(W1, g1, b1, m1, v1, flag, Wb1, sc1, sh1, 288);
  cvtw_k<<<333, 256, 0, stream>>>(W2, g2, b2, m2, v2, flag, Wb2, sc2, sh2, 288);
  sort_k<<<NBAT, 1024, 0, stream>>>(X, Y, Z, X2, Y2, Z2, I2);
  fps_k<<<NBAT, 1024, 0, stream>>>(P4, X2, Y2, Z2, I2, flag, nxyz, d_out);
  ballq_k<<<1024, 256, 0, stream>>>(X, Y, Z, nxyz, bidx);
  gather_k<<<1024, 256, 0, stream>>>(xyz, feat, flag, bidx, nxyz, bufA);
  gemm_k<<<dim3(512,3), 256, 128*296*2, stream>>>(bufA, 296, Wb0, sc0, sh0, bufB, 288, 10, 296);
  gemm_k<<<dim3(512,3), 256, 128*288*2, stream>>>(bufB, 288, Wb1, sc1, sh1, bufA, 296, 9, 288);
  gemm_k<<<dim3(512,3), 256, 128*296*2, stream>>>(bufA, 296, Wb2, sc2, sh2, bufB, 288, 9, 288);
  maxk_k<<<512, 256, 0, stream>>>(bufB, flag, d_out);
}

// Round 4
// 934.889 us; speedup vs baseline: 1.3579x; 1.0794x over previous
//
#include <hip/hip_runtime.h>
#include <hip/hip_bf16.h>
#include <string.h>

#define NPT   16384
#define NBAT  16
#define CH    288
#define SP    256
#define KS    16
#define OFF_FEAT 12288L
#define OFF_IND  1191936L

// ---------- helpers ----------
__device__ __forceinline__ float bfbits(unsigned short u){
  unsigned int x = ((unsigned int)u) << 16; float f; __builtin_memcpy(&f,&x,4); return f;
}
__device__ __forceinline__ float ldf(const void* p, long i, int isb){
  if (isb) return __bfloat162float(((const __hip_bfloat16*)p)[i]);
  return ((const float*)p)[i];
}
__device__ __forceinline__ void sto(void* p, long i, float v, int isb){
  if (isb) ((__hip_bfloat16*)p)[i] = __float2bfloat16(v);
  else     ((float*)p)[i] = v;
}
__device__ __forceinline__ void gload_lds(const void* g, void* l){
  __builtin_amdgcn_global_load_lds((const __attribute__((address_space(1))) void*)g,
      (__attribute__((address_space(3))) void*)l, 16, 0, 0);
}
__device__ __forceinline__ unsigned spread4(unsigned x){
  return (x&1u) | ((x&2u)<<2) | ((x&4u)<<4) | ((x&8u)<<6);
}

typedef __attribute__((ext_vector_type(8))) short bf16x8;
typedef __attribute__((ext_vector_type(4))) float f32x4;
typedef __attribute__((ext_vector_type(2))) float f32x2;

// u64 max via DPP row_ror (VALU cross-lane, no DS). Max is associative+commutative,
// so any reduce network gives the bit-exact same result as the shfl butterfly.
template<int CTRL>
__device__ __forceinline__ unsigned long long ror_max64(unsigned long long k){
  int lo2 = __builtin_amdgcn_update_dpp(0, (int)(unsigned)k, CTRL, 0xf, 0xf, false);
  int hi2 = __builtin_amdgcn_update_dpp(0, (int)(unsigned)(k>>32), CTRL, 0xf, 0xf, false);
  unsigned long long o = ((unsigned long long)(unsigned)hi2 << 32) | (unsigned)lo2;
  return o > k ? o : k;
}
__device__ __forceinline__ unsigned long long rowmax64(unsigned long long k){
  k = ror_max64<0x121>(k);   // row_ror:1
  k = ror_max64<0x122>(k);   // row_ror:2
  k = ror_max64<0x124>(k);   // row_ror:4
  k = ror_max64<0x128>(k);   // row_ror:8  -> every lane holds max of its 16-lane row
  return k;
}
__device__ __forceinline__ unsigned long long rl64(unsigned long long v, int l){
  unsigned lo = (unsigned)__builtin_amdgcn_readlane((int)(unsigned)v, l);
  unsigned hi = (unsigned)__builtin_amdgcn_readlane((int)(unsigned)(v>>32), l);
  return (((unsigned long long)hi)<<32) | lo;
}

// ---------- 0. input dtype detection ----------
__global__ void detect_k(const void* __restrict__ xyz, int* __restrict__ flag){
  __shared__ float red[256];
  const int t = threadIdx.x;
  const unsigned short* u = (const unsigned short*)xyz;
  float m = 0.f;
  for (int i = t; i < 4096; i += 256){
    float f = fabsf(bfbits(u[i]));
    if (f != f) f = 1e30f;
    m = fmaxf(m, f);
  }
  red[t] = m; __syncthreads();
  for (int s = 128; s; s >>= 1){ if (t < s) red[t] = fmaxf(red[t], red[t+s]); __syncthreads(); }
  if (t == 0) *flag = (red[0] < 2.0f) ? 1 : 0;
}

// ---------- 0b. xyz -> f32 SoA + interleaved float4 (for fps center loads) ----------
__global__ __launch_bounds__(256) void cvtxyz_k(const void* __restrict__ xyz,
    const int* __restrict__ flag, float* __restrict__ X, float* __restrict__ Y,
    float* __restrict__ Z, float4* __restrict__ P4){
  const int n = blockIdx.x*256 + threadIdx.x;       // < 262144 points
  const int isb = *flag;
  float x = ldf(xyz, (long)n*3+0, isb);
  float y = ldf(xyz, (long)n*3+1, isb);
  float z = ldf(xyz, (long)n*3+2, isb);
  X[n] = x; Y[n] = y; Z[n] = z;                     // n == b*NPT+i (NPT=2^14)
  P4[n] = make_float4(x, y, z, 0.f);
}

// ---------- 0c. W -> bf16 [288][296] + BN scale/shift ----------
__global__ __launch_bounds__(256) void cvtw_k(const void* __restrict__ W,
    const void* __restrict__ g, const void* __restrict__ bb,
    const void* __restrict__ m, const void* __restrict__ v,
    const int* __restrict__ flag, __hip_bfloat16* __restrict__ Wbf,
    float* __restrict__ scale, float* __restrict__ shift, int Kin){
  const int isb = *flag;
  const int idx = blockIdx.x*256 + threadIdx.x;
  if (idx < 288*296){
    int o = idx / 296, k = idx - o*296;
    float val = (k < Kin) ? ldf(W, (long)o*Kin + k, isb) : 0.f;
    Wbf[idx] = __float2bfloat16(val);
  }
  if (idx < 288){
    float sc = ldf(g, idx, isb) * rsqrtf(ldf(v, idx, isb) + 1e-5f);
    scale[idx] = sc;
    shift[idx] = ldf(bb, idx, isb) - ldf(m, idx, isb)*sc;
  }
}

// ---------- 0d. Morton bucket sort (per batch): spatial clustering for FPS pruning ----------
// Any permutation is valid: fps uses I2 (original indices) for exact argmax tiebreak.
__global__ __launch_bounds__(1024) void sort_k(const float* __restrict__ X,
    const float* __restrict__ Y, const float* __restrict__ Z,
    float* __restrict__ X2, float* __restrict__ Y2, float* __restrict__ Z2,
    int* __restrict__ I2){
  __shared__ int hist[4096];
  __shared__ int wtot[16];
  const int b = blockIdx.x, t = threadIdx.x, base = b*NPT;
  for (int j = t; j < 4096; j += 1024) hist[j] = 0;
  __syncthreads();
  int cell[16]; float lx[16], ly[16], lz[16];
  #pragma unroll
  for (int i=0;i<16;i++){
    const int id = t + i*1024;
    float x = X[base+id], y = Y[base+id], z = Z[base+id];
    lx[i]=x; ly[i]=y; lz[i]=z;
    int cx = (int)(x*16.f); cx = cx<0?0:(cx>15?15:cx);
    int cy = (int)(y*16.f); cy = cy<0?0:(cy>15?15:cy);
    int cz = (int)(z*16.f); cz = cz<0?0:(cz>15?15:cz);
    cell[i] = (int)(spread4((unsigned)cx) | (spread4((unsigned)cy)<<1) | (spread4((unsigned)cz)<<2));
    atomicAdd(&hist[cell[i]], 1);
  }
  __syncthreads();
  // exclusive scan over 4096 bins (4 bins/thread)
  int s0 = hist[t*4], s1 = hist[t*4+1], s2 = hist[t*4+2], s3 = hist[t*4+3];
  int ls = s0+s1+s2+s3;
  int sc = ls;
  #pragma unroll
  for (int off=1; off<64; off<<=1){
    int o = __shfl_up(sc, off, 64);
    if ((t&63) >= off) sc += o;
  }
  if ((t&63) == 63) wtot[t>>6] = sc;
  __syncthreads();
  int wpre = 0;
  #pragma unroll
  for (int w=0; w<16; w++) wpre += (w < (t>>6)) ? wtot[w] : 0;
  const int ebase = wpre + sc - ls;
  hist[t*4]   = ebase;
  hist[t*4+1] = ebase + s0;
  hist[t*4+2] = ebase + s0 + s1;
  hist[t*4+3] = ebase + s0 + s1 + s2;
  __syncthreads();
  #pragma unroll
  for (int i=0;i<16;i++){
    const int dst = atomicAdd(&hist[cell[i]], 1);
    X2[base+dst] = lx[i]; Y2[base+dst] = ly[i]; Z2[base+dst] = lz[i];
    I2[base+dst] = t + i*1024;
  }
}

// ---------- 1. FPS: DPP argmax reduce + per-pair (128-pt) bit-exact prune ----------
// Each wave owns 1024 Morton-contiguous pts as 8 pairs of 64-pt columns (f32x2 regs).
// Per iter: lane l tests pair l&7's bbox lower-bound vs wavemax; uniform 8-bit mask
// skips provably-unchanged pairs (cached per-pair key pk[j] stays exact: dists only
// move when updated, and skip condition guarantees d2 > wavemax >= dist bitwise).
// All argmax reduces via DPP row_ror + readlane (VALU/SALU; no ds_bpermute chains).
__global__ __launch_bounds__(1024) __attribute__((amdgpu_waves_per_eu(4,4)))
void fps_k(const float4* __restrict__ P4,
    const float* __restrict__ X2, const float* __restrict__ Y2,
    const float* __restrict__ Z2, const int* __restrict__ I2,
    const int* __restrict__ flag, float* __restrict__ nxyz, void* __restrict__ dout){
  #pragma clang fp contract(off)
  const int b = blockIdx.x, t = threadIdx.x;
  const int base = b*NPT;
  const int lane = t & 63, wid = t >> 6;
  f32x2 px[8], py[8], pz[8], ds[8];
  unsigned li2[8];
  unsigned long long pk[8];
  const int p0 = base + wid*1024 + lane;
  #pragma unroll
  for (int j=0;j<8;j++){
    px[j] = (f32x2){X2[p0 + (2*j)*64], X2[p0 + (2*j+1)*64]};
    py[j] = (f32x2){Y2[p0 + (2*j)*64], Y2[p0 + (2*j+1)*64]};
    pz[j] = (f32x2){Z2[p0 + (2*j)*64], Z2[p0 + (2*j+1)*64]};
    unsigned a = 16383u - (unsigned)I2[p0 + (2*j)*64];
    unsigned c = 16383u - (unsigned)I2[p0 + (2*j+1)*64];
    li2[j] = a | (c<<16);
    ds[j] = (f32x2){1e10f, 1e10f};
    pk[j] = 0ull;
  }
  // per-pair bboxes; lane ends up holding pair (lane&7)'s bbox
  float pnx=0.f, pxx=0.f, pny=0.f, pxy=0.f, pnz=0.f, pxz=0.f;
  const int myp = lane & 7;
  #pragma unroll
  for (int j=0;j<8;j++){
    float nx = fminf(px[j].x,px[j].y), xx = fmaxf(px[j].x,px[j].y);
    float ny = fminf(py[j].x,py[j].y), xy = fmaxf(py[j].x,py[j].y);
    float nz = fminf(pz[j].x,pz[j].y), xz = fmaxf(pz[j].x,pz[j].y);
    #pragma unroll
    for (int off=32; off; off>>=1){
      nx = fminf(nx, __shfl_xor(nx, off, 64)); xx = fmaxf(xx, __shfl_xor(xx, off, 64));
      ny = fminf(ny, __shfl_xor(ny, off, 64)); xy = fmaxf(xy, __shfl_xor(xy, off, 64));
      nz = fminf(nz, __shfl_xor(nz, off, 64)); xz = fmaxf(xz, __shfl_xor(xz, off, 64));
    }
    if (myp == j){ pnx=nx; pxx=xx; pny=ny; pxy=xy; pnz=nz; pxz=xz; }
  }
  __shared__ unsigned long long slot[2][16];
  __shared__ float ox[SP], oy[SP], oz[SP];
  __shared__ int   oi[SP];
  float4 c4 = P4[base];
  float cx = c4.x, cy = c4.y, cz = c4.z;
  int cur = 0;
  unsigned long long wk = 0ull;
  float wavemax = 1e30f;
  for (int it=0; it<SP; it++){
    if (t == 0){ ox[it]=cx; oy[it]=cy; oz[it]=cz; oi[it]=cur; }
    // pair-grain prune: lane l computes lb for pair l&7 (lanes 8..63 replicate 0..7)
    float ddx = fmaxf(fmaxf(pnx-cx, cx-pxx), 0.f);
    float ddy = fmaxf(fmaxf(pny-cy, cy-pxy), 0.f);
    float ddz = fmaxf(fmaxf(pnz-cz, cz-pxz), 0.f);
    float lb = ddx*ddx + ddy*ddy; lb = lb + ddz*ddz;
    unsigned mask = (unsigned)__ballot(!(lb * 0.9999f > wavemax)) & 0xffu;
    mask = (unsigned)__builtin_amdgcn_readfirstlane((int)mask);
    if (mask){
      const f32x2 Cx = {cx,cx}, Cy = {cy,cy}, Cz = {cz,cz};
      #define UPD(j) if (mask & (1u<<(j))) { \
        f32x2 dx = px[j]-Cx, dy = py[j]-Cy, dz = pz[j]-Cz; \
        f32x2 m0 = dx*dx, m1 = dy*dy, m2 = dz*dz; \
        f32x2 d2 = (m0+m1)+m2; \
        f32x2 dn = __builtin_elementwise_min(ds[j], d2); \
        ds[j] = dn; \
        unsigned long long k0 = ((unsigned long long)__float_as_uint(dn.x)<<32) | (unsigned long long)(li2[j] & 0xFFFFu); \
        unsigned long long k1 = ((unsigned long long)__float_as_uint(dn.y)<<32) | (unsigned long long)(li2[j] >> 16); \
        pk[j] = (k0 > k1) ? k0 : k1; }
      UPD(0) UPD(1) UPD(2) UPD(3) UPD(4) UPD(5) UPD(6) UPD(7)
      #undef UPD
      unsigned long long best = pk[0];
      #pragma unroll
      for (int j=1;j<8;j++) best = (pk[j] > best) ? pk[j] : best;
      best = rowmax64(best);
      // cross-row combine in SGPRs (uniform)
      unsigned long long r0 = rl64(best, 0),  r1 = rl64(best, 16);
      unsigned long long r2 = rl64(best, 32), r3 = rl64(best, 48);
      unsigned long long a01 = (r0 > r1) ? r0 : r1;
      unsigned long long a23 = (r2 > r3) ? r2 : r3;
      wk = (a01 > a23) ? a01 : a23;
      wavemax = __uint_as_float((unsigned)(wk >> 32));
    }
    const int p = it & 1;
    if (lane == 0) slot[p][wid] = wk;
    __syncthreads();
    // each row's 16 lanes hold all 16 slots -> 4 ror levels give the global max
    unsigned long long g = slot[p][lane & 15];
    g = rowmax64(g);
    cur = 16383 - (int)(unsigned)g;
    cur = __builtin_amdgcn_readfirstlane(cur);
    c4 = P4[base+cur];
    cx = c4.x; cy = c4.y; cz = c4.z;
  }
  __syncthreads();
  if (t < SP){
    const int isb = *flag;
    const long bs = (long)b*SP + t;
    float fx=ox[t], fy=oy[t], fz=oz[t]; int ii=oi[t];
    nxyz[bs*3+0]=fx; nxyz[bs*3+1]=fy; nxyz[bs*3+2]=fz;
    sto(dout, bs*3+0, fx, isb);
    sto(dout, bs*3+1, fy, isb);
    sto(dout, bs*3+2, fz, isb);
    sto(dout, OFF_IND + bs, (float)ii, isb);
  }
}

// ---------- 2. ball query (SoA f32) ----------
__global__ __launch_bounds__(256) void ballq_k(const float* __restrict__ X,
    const float* __restrict__ Y, const float* __restrict__ Z,
    const float* __restrict__ nxyz, int* __restrict__ bidx){
  #pragma clang fp contract(off)
  const int gw = (blockIdx.x*256 + threadIdx.x) >> 6;
  const int lane = threadIdx.x & 63;
  const int b = gw >> 8, base = b*NPT;
  const float cx = nxyz[gw*3+0], cy = nxyz[gw*3+1], cz = nxyz[gw*3+2];
  int cnt = 0, first = 0; bool havef = false;
  for (int st = 0; st < NPT && cnt < KS; st += 64){
    const int id = st + lane;
    float dx = X[base+id]-cx, dy = Y[base+id]-cy, dz = Z[base+id]-cz;
    float d2 = dx*dx + dy*dy; d2 = d2 + dz*dz;
    unsigned long long mk = __ballot(d2 <= 0.09f);  // == (f32 d2 < double 0.09)
    if (mk){
      if (!havef){ first = st + __builtin_ctzll(mk); havef = true; }
      int rank = cnt + __popcll(mk & ((1ull<<lane)-1ull));
      if (((mk>>lane)&1ull) && rank < KS) bidx[gw*KS + rank] = id;
      cnt += __popcll(mk);
    }
  }
  if (cnt < KS && lane >= cnt && lane < KS) bidx[gw*KS + lane] = first;
}

// ---------- 3. gather -> h0 [n][296] bf16 via LDS tile ----------
__global__ __launch_bounds__(256) void gather_k(const void* __restrict__ xyz,
    const void* __restrict__ feat, const int* __restrict__ flag,
    const int* __restrict__ bidx, const float* __restrict__ nxyz,
    __hip_bfloat16* __restrict__ h0){
  __shared__ __hip_bfloat16 tile[64*296];
  const int isb = *flag;
  const int t = threadIdx.x, n0 = blockIdx.x*64;
  const int nl = t >> 2, cg = t & 3;
  const int n = n0 + nl, b = n >> 12, s = n >> 4;
  const int id = bidx[n];
  for (int j=0; j<74; j++){
    int c = cg*74 + j;
    float vv = 0.f;
    if (c < 3)       vv = (ldf(xyz, ((long)b*NPT + id)*3 + c, isb) - nxyz[(long)s*3 + c]) / 0.3f;
    else if (c < 291) vv = ldf(feat, ((long)b*CH + (c-3))*(long)NPT + id, isb);
    tile[nl*296 + c] = __float2bfloat16(vv);
  }
  __syncthreads();
  const uint4* src = (const uint4*)tile;
  uint4* dst = (uint4*)((char*)h0 + (long)n0*592);
  for (int j = t; j < 2368; j += 256) dst[j] = src[j];
}

// ---------- 4. MFMA GEMM: Out[n][o] = relu(BN(sum_k A[n][k]*W[o][k])) ----------
// Block tile 128n x 96o, whole-K A-tile in LDS (global_load_lds), W frags from L2.
__global__ __launch_bounds__(256, 2) void gemm_k(
    const __hip_bfloat16* __restrict__ A, int astr,
    const __hip_bfloat16* __restrict__ W,
    const float* __restrict__ scale, const float* __restrict__ shift,
    __hip_bfloat16* __restrict__ Out, int ostr,
    int ktiles, int kvalid){
  extern __shared__ char lds[];
  const int t = threadIdx.x, lane = t & 63, wid = t >> 6;
  const int wm = wid & 1, wo = wid >> 1;
  const int bx = blockIdx.x, by = blockIdx.y;
  {
    const char* src = (const char*)(A + (long)bx*128*astr);
    const int chunks = (128*astr*2) >> 10;
    for (int c = wid; c < chunks; c += 4)
      gload_lds(src + c*1024 + lane*16, lds + c*1024);
  }
  f32x4 acc[4][3];
  #pragma unroll
  for (int mf=0; mf<4; mf++)
    #pragma unroll
    for (int of=0; of<3; of++) acc[mf][of] = (f32x4){0.f,0.f,0.f,0.f};

  const int mrow  = wm*64 + (lane & 15);
  const int kg    = (lane >> 4) * 8;
  const int obase = by*96 + wo*48 + (lane & 15);
  __syncthreads();

  for (int kt = 0; kt < ktiles; kt++){
    const int k0 = kt*32 + kg;
    const bool z = (k0 >= kvalid);
    const int k0c = z ? 0 : k0;
    bf16x8 a[4], bf[3];
    #pragma unroll
    for (int mf=0; mf<4; mf++)
      a[mf] = *(const bf16x8*)(lds + ((long)(mrow + mf*16)*astr + k0c)*2);
    if (z){
      bf16x8 zz = {0,0,0,0,0,0,0,0};
      #pragma unroll
      for (int mf=0; mf<4; mf++) a[mf] = zz;
    }
    #pragma unroll
    for (int of=0; of<3; of++)
      bf[of] = *(const bf16x8*)(W + (long)(obase + of*16)*296 + k0c);
    #pragma unroll
    for (int mf=0; mf<4; mf++)
      #pragma unroll
      for (int of=0; of<3; of++)
        acc[mf][of] = __builtin_amdgcn_mfma_f32_16x16x32_bf16(a[mf], bf[of], acc[mf][of], 0, 0, 0);
  }

  float sc[3], sh[3];
  #pragma unroll
  for (int of=0; of<3; of++){ sc[of] = scale[obase + of*16]; sh[of] = shift[obase + of*16]; }
  #pragma unroll
  for (int mf=0; mf<4; mf++)
    #pragma unroll
    for (int of=0; of<3; of++)
      #pragma unroll
      for (int r=0; r<4; r++){
        const long row = (long)bx*128 + wm*64 + mf*16 + (lane>>4)*4 + r;
        const int o = obase + of*16;
        float vv = acc[mf][of][r]*sc[of] + sh[of];
        Out[row*ostr + o] = __float2bfloat16(fmaxf(vv, 0.f));
      }
}

// ---------- 5. maxpool over k: h[n][288] -> out[b][o][s] ----------
__global__ __launch_bounds__(256) void maxk_k(const __hip_bfloat16* __restrict__ h,
    const int* __restrict__ flag, void* __restrict__ dout){
  __shared__ __hip_bfloat16 tile[128*288];
  const int isb = *flag;
  const int t = threadIdx.x;
  const int b = blockIdx.x >> 5, s0 = (blockIdx.x & 31)*8;
  const long n0 = (long)b*4096 + (long)s0*16;
  {
    const char* src = (const char*)(h + n0*288);
    for (int c = (t>>6); c < 72; c += 4)
      gload_lds(src + c*1024 + (t&63)*16, (char*)tile + c*1024);
  }
  __syncthreads();
  for (int o = t; o < 288; o += 256){
    float mx[8];
    #pragma unroll
    for (int sl=0; sl<8; sl++){
      float m = -1e30f;
      #pragma unroll
      for (int kk=0; kk<16; kk++)
        m = fmaxf(m, __bfloat162float(tile[(sl*16 + kk)*288 + o]));
      mx[sl] = m;
    }
    const long e0 = OFF_FEAT + (long)b*73728 + (long)o*256 + s0;
    if (isb){
      unsigned short u[8];
      #pragma unroll
      for (int sl=0; sl<8; sl++){
        __hip_bfloat16 hb = __float2bfloat16(mx[sl]);
        __builtin_memcpy(&u[sl], &hb, 2);
      }
      uint4 pk; __builtin_memcpy(&pk, u, 16);
      *(uint4*)((__hip_bfloat16*)dout + e0) = pk;
    } else {
      float* fo = (float*)dout + e0;
      *(float4*)fo     = make_float4(mx[0],mx[1],mx[2],mx[3]);
      *(float4*)(fo+4) = make_float4(mx[4],mx[5],mx[6],mx[7]);
    }
  }
}

extern "C" void kernel_launch(void* const* d_in, const int* in_sizes, int n_in,
                              void* d_out, int out_size, void* d_ws, size_t ws_size,
                              hipStream_t stream){
  const void* xyz  = d_in[0];
  const void* feat = d_in[1];
  const void* W0 = d_in[2];  const void* g0 = d_in[3];  const void* b0 = d_in[4];
  const void* m0 = d_in[5];  const void* v0 = d_in[6];
  const void* W1 = d_in[7];  const void* g1 = d_in[8];  const void* b1 = d_in[9];
  const void* m1 = d_in[10]; const void* v1 = d_in[11];
  const void* W2 = d_in[12]; const void* g2 = d_in[13]; const void* b2 = d_in[14];
  const void* m2 = d_in[15]; const void* v2 = d_in[16];

  char* ws = (char*)d_ws;
  int*   flag  = (int*)ws;                                   // [0,64)
  float* sc0   = (float*)(ws + 64);                          // 3x(288+288) f32
  float* sh0   = sc0 + 288;
  float* sc1   = sc0 + 576;  float* sh1 = sc0 + 864;
  float* sc2   = sc0 + 1152; float* sh2 = sc0 + 1440;
  __hip_bfloat16* Wb0 = (__hip_bfloat16*)(ws + 7040);        // 288*296*2 = 170496
  __hip_bfloat16* Wb1 = Wb0 + 288*296;
  __hip_bfloat16* Wb2 = Wb1 + 288*296;                       // ends @ 518528
  float* nxyz = (float*)(ws + 518656);                       // 49152 -> 567808
  int*   bidx = (int*)(ws + 567808);                         // 262144 -> 829952
  float* X    = (float*)(ws + 1048576);                      // overlaid with bufA (dead after ballq)
  float* Y    = X + NBAT*NPT;
  float* Z    = Y + NBAT*NPT;
  float4* P4  = (float4*)(ws + 1048576 + 3145728);           // 4 MiB, dead after fps
  __hip_bfloat16* bufA = (__hip_bfloat16*)(ws + 1048576);    // [65536][296] = 38797312
  __hip_bfloat16* bufB = (__hip_bfloat16*)(ws + 1048576 + 38797312); // [65536][288] -> end 77594624
  // Morton-sorted copies, overlaid on bufB (dead before gemm#1 writes bufB)
  float* X2 = (float*)bufB;
  float* Y2 = X2 + NBAT*NPT;
  float* Z2 = Y2 + NBAT*NPT;
  int*   I2 = (int*)(Z2 + NBAT*NPT);                         // 4 MiB total << 37 MiB

  detect_k<<<1, 256, 0, stream>>>(xyz, flag);
  cvtxyz_k<<<1024, 256, 0, stream>>>(xyz, flag, X, Y, Z, P4);
  cvtw_k<<<333, 256, 0, stream>>>(W0, g0, b0, m0, v0, flag, Wb0, sc0, sh0, 291);
  cvtw_k<<<333, 256, 0, stream>>>(W1, g1, b1, m1, v1, flag, Wb1, sc1, sh1, 288);
  cvtw_k<<<333, 256, 0, stream>>>(W2, g2, b2, m2, v2, flag, Wb2, sc2, sh2, 288);
  sort_k<<<NBAT, 1024, 0, stream>>>(X, Y, Z, X2, Y2, Z2, I2);
  fps_k<<<NBAT, 1024, 0, stream>>>(P4, X2, Y2, Z2, I2, flag, nxyz, d_out);
  ballq_k<<<1024, 256, 0, stream>>>(X, Y, Z, nxyz, bidx);
  gather_k<<<1024, 256, 0, stream>>>(xyz, feat, flag, bidx, nxyz, bufA);
  gemm_k<<<dim3(512,3), 256, 128*296*2, stream>>>(bufA, 296, Wb0, sc0, sh0, bufB, 288, 10, 296);
  gemm_k<<<dim3(512,3), 256, 128*288*2, stream>>>(bufB, 288, Wb1, sc1, sh1, bufA, 296, 9, 288);
  gemm_k<<<dim3(512,3), 256, 128*296*2, stream>>>(bufA, 296, Wb2, sc2, sh2, bufB, 288, 9, 288);
  maxk_k<<<512, 256, 0, stream>>>(bufB, flag, d_out);
}